// Round 1
// baseline (236.494 us; speedup 1.0000x reference)
//
#include <hip/hip_runtime.h>

#define NB 128
#define CC 1024
#define HWP 196
#define HH 14
#define OO 256

typedef unsigned short ushort_t;
typedef __attribute__((ext_vector_type(8))) short short8;
typedef __attribute__((ext_vector_type(4))) float float4v;

__device__ __forceinline__ ushort_t f2bf(float v) {
  union { float f; unsigned int u; } c; c.f = v;
  unsigned int u = c.u;
  unsigned int r = (u + 0x7FFFu + ((u >> 16) & 1u)) >> 16;   // RNE
  return (ushort_t)r;
}

// K1: 26 blocks per n, interleaved for L3 locality on x:
//   r < 2  : partial channel-sum (one wave per (n,cg)). Component-wise
//            accumulation over c=0..127 ascending — bit-identical per-p FP
//            order to prior versions (medK rank selection is knife-edge
//            sensitive to this order; do NOT reorder the c loop).
//   r < 10 : bf16 transpose x(n,c,p) -> xt(n,p,c). Lane map: p fast (16/wave),
//            c-chunk slow (4/wave) -> reads cover whole 64B lines of x;
//            stores are 16 full 64B lines of xt per wave-instr. No LDS.
//   else   : bf16 weight cast.
__global__ __launch_bounds__(256) void k_prep(const float* __restrict__ x,
                                              const float* __restrict__ wmax,
                                              const float* __restrict__ wmed,
                                              float* __restrict__ partial,
                                              ushort_t* __restrict__ wb,
                                              ushort_t* __restrict__ xt) {
  const int bid = blockIdx.x, t = threadIdx.x;
  const int n = bid / 26, r = bid % 26;

  if (r >= 10) {   // ---- weight cast: 16 blocks/n * 128 n * 256 = 2*OO*CC ----
    int idx = (n * 16 + (r - 10)) * 256 + t;
    int z = idx >> 18;
    int rr = idx & (OO * CC - 1);
    const float* w = z ? wmed : wmax;
    wb[idx] = f2bf(w[rr]);
    return;
  }

  if (r >= 2) {    // ---- transpose: 8 blocks/n, one per 128-channel group ----
    const int cg = r - 2;
    const int pl = t & 15;          // p low bits: fast across lanes
    const int ch = t >> 4;          // 16 chunks of 8 channels: slow across lanes
    const float* xb = x + ((size_t)n * CC + cg * 128 + ch * 8) * HWP;
    ushort_t* xo = xt + (size_t)n * HWP * CC + cg * 128 + ch * 8;
    #pragma unroll 2
    for (int it = 0; it <= 12; ++it) {
      const int p = pl + 16 * it;
      if (p < HWP) {
        float v[8];
        #pragma unroll
        for (int j = 0; j < 8; ++j) v[j] = xb[(size_t)j * HWP + p];
        short8 o;
        #pragma unroll
        for (int j = 0; j < 8; ++j) o[j] = (short)f2bf(v[j]);
        *(short8*)(xo + (size_t)p * CC) = o;
      }
    }
    return;
  }

  // ---- reduce: unit mapping identical to prior version (bit-exact) ----
  const int unit = (n * 2 + r) * 4 + (t >> 6);   // (n,cg) unit, one per wave
  const int lane = t & 63;
  if (lane >= 49) return;                        // 49 float4s cover 196 floats
  const int nn = unit >> 3, cg = unit & 7;
  const float4* base = (const float4*)(x + ((size_t)nn * CC + (size_t)cg * 128) * HWP);
  float4 s = {0.f, 0.f, 0.f, 0.f};
  #pragma unroll 16
  for (int c = 0; c < 128; ++c) {
    float4 v = base[c * 49 + lane];
    s.x += v.x; s.y += v.y; s.z += v.z; s.w += v.w;   // per-p sequential order
  }
  ((float4*)(partial + ((size_t)nn * 8 + cg) * HWP))[lane] = s;
}

// K2: per (n,z) block, 512 threads (8 waves): in-block exact stable rank-select;
// A-load is now a fully-coalesced 32 KB bf16 copy from xt (transpose + f2bf
// were hoisted into k_prep); bf16 MFMA GEMM (8 waves x 32 cols); BN+ReLU;
// Lnorm apply; writes graphs (+ rows/cols from z==0 blocks).
__global__ __launch_bounds__(512, 2) void k_main(
    const float* __restrict__ partial,
    const ushort_t* __restrict__ wb,
    const ushort_t* __restrict__ xt,
    const float* __restrict__ g_max, const float* __restrict__ b_max,
    const float* __restrict__ m_max, const float* __restrict__ v_max,
    const float* __restrict__ g_med, const float* __restrict__ b_med,
    const float* __restrict__ m_med, const float* __restrict__ v_med,
    float* __restrict__ out) {
  constexpr int AP = 1032;               // padded row stride (ushorts)
  __shared__ alignas(16) ushort_t A_sh[16 * AP];   // 33 KB
  __shared__ float fre[HWP];
  __shared__ int sc[32];
  __shared__ float Lsh[16][17];
  __shared__ float dinv[16];
  __shared__ float y_sh[16][257];        // 16.4 KB

  const int n = blockIdx.x;
  const int z = blockIdx.y;
  const int t = threadIdx.x;

  // ---- select: fre = sum of 8 partials (sequential); stable ranks ----
  if (t < HWP) {
    float s = 0.f;
    #pragma unroll
    for (int g = 0; g < 8; ++g) s += partial[((size_t)n * 8 + g) * HWP + t];
    fre[t] = s;
  }
  __syncthreads();
  if (t < HWP) {
    float v = fre[t];
    int rank = 0;
    #pragma unroll 4
    for (int q = 0; q < HWP; ++q) {
      float u = fre[q];
      rank += ((u > v) || (u == v && q < t)) ? 1 : 0;
    }
    if (rank < 16) sc[rank] = t;                           // maxK: ranks 0..15
    else if (rank >= 89 && rank < 105) sc[rank - 73] = t;  // medK: ranks 89..104
  }
  __syncthreads();

  if (z == 0 && t < 32) {
    int p = sc[t];
    out[2 * NB * 4096 + n * 32 + t] = (float)(p / HH);            // rows
    out[2 * NB * 4096 + NB * 32 + n * 32 + t] = (float)(p % HH);  // cols
  }

  // ---- A load: 16 rows x 2 KB from xt, fully coalesced (512 B / wave-instr) ----
  {
    const int j = t >> 5;              // row 0..15
    const int u = t & 31;              // 32 threads per row
    const ushort_t* src = xt + ((size_t)n * HWP + sc[z * 16 + j]) * CC + u * 8;
    ushort_t* dst = &A_sh[j * AP + u * 8];
    #pragma unroll
    for (int q = 0; q < 4; ++q)
      *(short8*)(dst + q * 256) = *(const short8*)(src + q * 256);
  }
  // ---- L matrix ----
  if (t < 256) {
    const int i = t >> 4, j = t & 15;
    int pi = sc[z * 16 + i], pj = sc[z * 16 + j];
    float dr = (float)(pi / HH - pj / HH);
    float dc = (float)(pi % HH - pj % HH);
    Lsh[i][j] = 1.0f / (1.0f + sqrtf(dr * dr + dc * dc));
  }
  __syncthreads();
  if (t < 16) {
    float s = 0.f;
    #pragma unroll
    for (int j = 0; j < 16; ++j) s += Lsh[t][j];
    dinv[t] = rsqrtf(s);
  }

  const int w = t >> 6;                  // 8 waves, 32 output cols each
  const int l = t & 63;
  const int m = l & 15;
  const int quad = l >> 4;

  const ushort_t* Arow = &A_sh[m * AP + quad * 8];
  const ushort_t* B0 = wb + (size_t)z * (OO * CC) + (size_t)(w * 32 + m) * CC + quad * 8;

  float4v acc0 = {0.f, 0.f, 0.f, 0.f};
  float4v acc1 = acc0;

  __syncthreads();   // dinv + A_sh visible

  #pragma unroll 4
  for (int k0 = 0; k0 < CC; k0 += 32) {
    short8 a  = *reinterpret_cast<const short8*>(Arow + k0);
    short8 b0 = *reinterpret_cast<const short8*>(B0 + k0);
    short8 b1 = *reinterpret_cast<const short8*>(B0 + 16 * CC + k0);
    acc0 = __builtin_amdgcn_mfma_f32_16x16x32_bf16(a, b0, acc0, 0, 0, 0);
    acc1 = __builtin_amdgcn_mfma_f32_16x16x32_bf16(a, b1, acc1, 0, 0, 0);
  }

  const float* gp = z ? g_med : g_max;
  const float* bp = z ? b_med : b_max;
  const float* mp = z ? m_med : m_max;
  const float* vp = z ? v_med : v_max;

  // BN + ReLU; scatter C-layout (col=lane&15, row=quad*4+reg) to LDS
  #pragma unroll
  for (int tt = 0; tt < 2; ++tt) {
    float4v av = tt ? acc1 : acc0;
    int o = w * 32 + tt * 16 + m;
    float scale = gp[o] * rsqrtf(vp[o] + 1e-5f);
    float shift = bp[o] - mp[o] * scale;
    #pragma unroll
    for (int r = 0; r < 4; ++r) {
      int j = quad * 4 + r;
      float y = av[r] * scale + shift;
      y = fmaxf(y, 0.f);
      y_sh[j][o] = y * dinv[j];
    }
  }
  __syncthreads();

  // out[n,z,i,o] = dinv_i * sum_j L[i][j] * (dinv_j * y[j][o])
  // 512 threads: o = t&255, half-i-range per t>>8
  {
    const int o = t & 255;
    const int ih = (t >> 8) * 8;
    float yp[16];
    #pragma unroll
    for (int j = 0; j < 16; ++j) yp[j] = y_sh[j][o];
    float* ob = out + (size_t)z * (NB * 4096) + (size_t)n * 4096 + o;
    #pragma unroll
    for (int i2 = 0; i2 < 8; ++i2) {
      const int i = ih + i2;
      float s = 0.f;
      #pragma unroll
      for (int j = 0; j < 16; ++j) s = fmaf(Lsh[i][j], yp[j], s);
      ob[(size_t)i * OO] = s * dinv[i];
    }
  }
}

extern "C" void kernel_launch(void* const* d_in, const int* in_sizes, int n_in,
                              void* d_out, int out_size, void* d_ws, size_t ws_size,
                              hipStream_t stream) {
  const float* x     = (const float*)d_in[0];
  const float* w_max = (const float*)d_in[2];
  const float* g_max = (const float*)d_in[3];
  const float* b_max = (const float*)d_in[4];
  const float* m_max = (const float*)d_in[5];
  const float* v_max = (const float*)d_in[6];
  const float* w_med = (const float*)d_in[7];
  const float* g_med = (const float*)d_in[8];
  const float* b_med = (const float*)d_in[9];
  const float* m_med = (const float*)d_in[10];
  const float* v_med = (const float*)d_in[11];
  float* out = (float*)d_out;

  float* ws_f = (float*)d_ws;
  float* partial  = ws_f;                        // 128*8*196 floats  (0.80 MB)
  ushort_t* wb    = (ushort_t*)(ws_f + 200704);  // 2*256*1024 ushorts (1 MB)
  ushort_t* xt    = wb + 2 * OO * CC;            // 128*196*1024 bf16 (51.4 MB)

  k_prep<<<dim3(26 * NB), 256, 0, stream>>>(x, w_max, w_med, partial, wb, xt);
  k_main<<<dim3(NB, 2), 512, 0, stream>>>(partial, wb, xt,
                                          g_max, b_max, m_max, v_max,
                                          g_med, b_med, m_med, v_med, out);
}

// Round 2
// 221.916 us; speedup vs baseline: 1.0657x; 1.0657x over previous
//
#include <hip/hip_runtime.h>

#define NB 128
#define CC 1024
#define HWP 196
#define HH 14
#define OO 256

typedef unsigned short ushort_t;
typedef __attribute__((ext_vector_type(4))) short short4v;
typedef __attribute__((ext_vector_type(8))) short short8;
typedef __attribute__((ext_vector_type(4))) float float4v;

__device__ __forceinline__ ushort_t f2bf(float v) {
  union { float f; unsigned int u; } c; c.f = v;
  unsigned int u = c.u;
  unsigned int r = (u + 0x7FFFu + ((u >> 16) & 1u)) >> 16;   // RNE
  return (ushort_t)r;
}

// K1 (identical to the proven R0 version): fused (a) partial channel-sum,
// (b) weight bf16 cast.
// Reduce: one wave per (n,cg); lanes 0..48 hold float4 (4 consecutive p).
// Component-wise accumulation over c=0..127 ascending — bit-identical per-p
// FP order (medK rank selection is knife-edge sensitive to this order;
// do NOT reorder the c loop).
__global__ __launch_bounds__(256) void k_prep(const float* __restrict__ x,
                                              const float* __restrict__ wmax,
                                              const float* __restrict__ wmed,
                                              float* __restrict__ partial,
                                              ushort_t* __restrict__ wb) {
  const int b = blockIdx.x, t = threadIdx.x;
  if (b >= 256) {   // weight cast: 2048 blocks x 256 = 2*OO*CC elements
    int idx = (b - 256) * 256 + t;
    int z = idx >> 18;
    int r = idx & (OO * CC - 1);
    const float* w = z ? wmed : wmax;
    wb[idx] = f2bf(w[r]);
    return;
  }
  const int unit = b * 4 + (t >> 6);     // (n,cg) unit, one per wave
  const int lane = t & 63;
  if (lane >= 49) return;                // 49 float4s cover 196 floats
  const int n = unit >> 3, cg = unit & 7;
  const float4 * base = (const float4*)(x + ((size_t)n * CC + (size_t)cg * 128) * HWP);
  float4 s = {0.f, 0.f, 0.f, 0.f};
  #pragma unroll 16
  for (int c = 0; c < 128; ++c) {
    float4 v = base[c * 49 + lane];
    s.x += v.x; s.y += v.y; s.z += v.z; s.w += v.w;   // per-p sequential order
  }
  ((float4*)(partial + ((size_t)n * 8 + cg) * HWP))[lane] = s;
}

// K1.5: extract pass. Block = (n, 128-channel group); 256 threads (4 waves).
// Recomputes the stable rank-select (bit-identical code to k_main), then each
// wave streams 32 contiguous channel-rows of x fully coalesced (49 lanes x
// float4 = whole 784B row), stages the row in LDS, and extracts only the 32
// selected positions -> A_f[n][j][c] bf16 (j = sc index 0..31, c contiguous).
// Each x line is read exactly once (L3-resident after K1) — this replaces
// k_main's 16x-amplified scattered gather.
__global__ __launch_bounds__(256) void k_extract(const float* __restrict__ x,
                                                 const float* __restrict__ partial,
                                                 ushort_t* __restrict__ af) {
  __shared__ float fre[HWP];
  __shared__ int sc[32];
  __shared__ float rowbuf[4][200];          // per-wave row stage
  __shared__ ushort_t outbuf[4][32][36];    // per-wave [j][c-local], pad 36

  const int b = blockIdx.x;
  const int n = b >> 3, cg = b & 7;
  const int t = threadIdx.x;

  // ---- rank select: EXACT same ops/order as k_main (must stay identical) ----
  if (t < HWP) {
    float s = 0.f;
    #pragma unroll
    for (int g = 0; g < 8; ++g) s += partial[((size_t)n * 8 + g) * HWP + t];
    fre[t] = s;
  }
  __syncthreads();
  if (t < HWP) {
    float v = fre[t];
    int rank = 0;
    #pragma unroll 4
    for (int q = 0; q < HWP; ++q) {
      float u = fre[q];
      rank += ((u > v) || (u == v && q < t)) ? 1 : 0;
    }
    if (rank < 16) sc[rank] = t;                           // maxK: ranks 0..15
    else if (rank >= 89 && rank < 105) sc[rank - 73] = t;  // medK: ranks 89..104
  }
  __syncthreads();

  const int w = t >> 6, lane = t & 63;
  const int c0 = cg * 128 + w * 32;               // 32 rows per wave
  const float* xrow = x + ((size_t)n * CC + c0) * HWP;
  const int sp = (lane < 32) ? sc[lane] : 0;

  float4 nxt = {0.f, 0.f, 0.f, 0.f};
  if (lane < 49) nxt = *(const float4*)(xrow + (size_t)lane * 4);
  for (int r = 0; r < 32; ++r) {
    float4 cur = nxt;
    if (r < 31 && lane < 49)
      nxt = *(const float4*)(xrow + (size_t)(r + 1) * HWP + (size_t)lane * 4);
    if (lane < 49) *(float4*)&rowbuf[w][lane * 4] = cur;
    // DS ops are in-order within a wave: read sees this iteration's write.
    if (lane < 32) outbuf[w][lane][r] = f2bf(rowbuf[w][sp]);
  }
  // ---- flush: A_f[n][j][c0..c0+31], 2 lanes per j (32B each, 8B-aligned) ----
  {
    const int j = lane & 31, half = lane >> 5;
    ushort_t* dst = af + ((size_t)n * 32 + j) * CC + c0 + half * 16;
    const ushort_t* srcp = &outbuf[w][j][half * 16];
    #pragma unroll
    for (int q = 0; q < 4; ++q)
      *(short4v*)(dst + q * 4) = *(const short4v*)(srcp + q * 4);
  }
}

// K2: per (n,z) block, 512 threads (8 waves): in-block exact stable rank-select;
// A-load is a fully coalesced 32 KB bf16 copy from A_f (scatter was hoisted to
// k_extract); bf16 MFMA GEMM (8 waves x 32 cols); BN+ReLU; Lnorm apply;
// writes graphs (+ rows/cols from z==0 blocks).
__global__ __launch_bounds__(512, 2) void k_main(
    const float* __restrict__ partial,
    const ushort_t* __restrict__ wb,
    const ushort_t* __restrict__ af,
    const float* __restrict__ g_max, const float* __restrict__ b_max,
    const float* __restrict__ m_max, const float* __restrict__ v_max,
    const float* __restrict__ g_med, const float* __restrict__ b_med,
    const float* __restrict__ m_med, const float* __restrict__ v_med,
    float* __restrict__ out) {
  constexpr int AP = 1032;               // padded row stride (ushorts)
  __shared__ alignas(16) ushort_t A_sh[16 * AP];   // 33 KB
  __shared__ float fre[HWP];
  __shared__ int sc[32];
  __shared__ float Lsh[16][17];
  __shared__ float dinv[16];
  __shared__ float y_sh[16][257];        // 16.4 KB

  const int n = blockIdx.x;
  const int z = blockIdx.y;
  const int t = threadIdx.x;

  // ---- select: fre = sum of 8 partials (sequential); stable ranks ----
  if (t < HWP) {
    float s = 0.f;
    #pragma unroll
    for (int g = 0; g < 8; ++g) s += partial[((size_t)n * 8 + g) * HWP + t];
    fre[t] = s;
  }
  __syncthreads();
  if (t < HWP) {
    float v = fre[t];
    int rank = 0;
    #pragma unroll 4
    for (int q = 0; q < HWP; ++q) {
      float u = fre[q];
      rank += ((u > v) || (u == v && q < t)) ? 1 : 0;
    }
    if (rank < 16) sc[rank] = t;                           // maxK: ranks 0..15
    else if (rank >= 89 && rank < 105) sc[rank - 73] = t;  // medK: ranks 89..104
  }
  __syncthreads();

  if (z == 0 && t < 32) {
    int p = sc[t];
    out[2 * NB * 4096 + n * 32 + t] = (float)(p / HH);            // rows
    out[2 * NB * 4096 + NB * 32 + n * 32 + t] = (float)(p % HH);  // cols
  }

  // ---- A load: 16 rows x 2 KB from A_f, fully coalesced ----
  {
    const int j = t >> 5;              // row 0..15
    const int u = t & 31;              // 32 threads per row
    const ushort_t* src = af + ((size_t)n * 32 + z * 16 + j) * CC + u * 8;
    ushort_t* dst = &A_sh[j * AP + u * 8];
    #pragma unroll
    for (int q = 0; q < 4; ++q)
      *(short8*)(dst + q * 256) = *(const short8*)(src + q * 256);
  }
  // ---- L matrix ----
  if (t < 256) {
    const int i = t >> 4, j = t & 15;
    int pi = sc[z * 16 + i], pj = sc[z * 16 + j];
    float dr = (float)(pi / HH - pj / HH);
    float dc = (float)(pi % HH - pj % HH);
    Lsh[i][j] = 1.0f / (1.0f + sqrtf(dr * dr + dc * dc));
  }
  __syncthreads();
  if (t < 16) {
    float s = 0.f;
    #pragma unroll
    for (int j = 0; j < 16; ++j) s += Lsh[t][j];
    dinv[t] = rsqrtf(s);
  }

  const int w = t >> 6;                  // 8 waves, 32 output cols each
  const int l = t & 63;
  const int m = l & 15;
  const int quad = l >> 4;

  const ushort_t* Arow = &A_sh[m * AP + quad * 8];
  const ushort_t* B0 = wb + (size_t)z * (OO * CC) + (size_t)(w * 32 + m) * CC + quad * 8;

  float4v acc0 = {0.f, 0.f, 0.f, 0.f};
  float4v acc1 = acc0;

  __syncthreads();   // dinv + A_sh visible

  #pragma unroll 4
  for (int k0 = 0; k0 < CC; k0 += 32) {
    short8 a  = *reinterpret_cast<const short8*>(Arow + k0);
    short8 b0 = *reinterpret_cast<const short8*>(B0 + k0);
    short8 b1 = *reinterpret_cast<const short8*>(B0 + 16 * CC + k0);
    acc0 = __builtin_amdgcn_mfma_f32_16x16x32_bf16(a, b0, acc0, 0, 0, 0);
    acc1 = __builtin_amdgcn_mfma_f32_16x16x32_bf16(a, b1, acc1, 0, 0, 0);
  }

  const float* gp = z ? g_med : g_max;
  const float* bp = z ? b_med : b_max;
  const float* mp = z ? m_med : m_max;
  const float* vp = z ? v_med : v_max;

  // BN + ReLU; scatter C-layout (col=lane&15, row=quad*4+reg) to LDS
  #pragma unroll
  for (int tt = 0; tt < 2; ++tt) {
    float4v av = tt ? acc1 : acc0;
    int o = w * 32 + tt * 16 + m;
    float scale = gp[o] * rsqrtf(vp[o] + 1e-5f);
    float shift = bp[o] - mp[o] * scale;
    #pragma unroll
    for (int r = 0; r < 4; ++r) {
      int j = quad * 4 + r;
      float y = av[r] * scale + shift;
      y = fmaxf(y, 0.f);
      y_sh[j][o] = y * dinv[j];
    }
  }
  __syncthreads();

  // out[n,z,i,o] = dinv_i * sum_j L[i][j] * (dinv_j * y[j][o])
  // 512 threads: o = t&255, half-i-range per t>>8
  {
    const int o = t & 255;
    const int ih = (t >> 8) * 8;
    float yp[16];
    #pragma unroll
    for (int j = 0; j < 16; ++j) yp[j] = y_sh[j][o];
    float* ob = out + (size_t)z * (NB * 4096) + (size_t)n * 4096 + o;
    #pragma unroll
    for (int i2 = 0; i2 < 8; ++i2) {
      const int i = ih + i2;
      float s = 0.f;
      #pragma unroll
      for (int j = 0; j < 16; ++j) s = fmaf(Lsh[i][j], yp[j], s);
      ob[(size_t)i * OO] = s * dinv[i];
    }
  }
}

extern "C" void kernel_launch(void* const* d_in, const int* in_sizes, int n_in,
                              void* d_out, int out_size, void* d_ws, size_t ws_size,
                              hipStream_t stream) {
  const float* x     = (const float*)d_in[0];
  const float* w_max = (const float*)d_in[2];
  const float* g_max = (const float*)d_in[3];
  const float* b_max = (const float*)d_in[4];
  const float* m_max = (const float*)d_in[5];
  const float* v_max = (const float*)d_in[6];
  const float* w_med = (const float*)d_in[7];
  const float* g_med = (const float*)d_in[8];
  const float* b_med = (const float*)d_in[9];
  const float* m_med = (const float*)d_in[10];
  const float* v_med = (const float*)d_in[11];
  float* out = (float*)d_out;

  float* ws_f = (float*)d_ws;
  float* partial  = ws_f;                        // 128*8*196 floats  (0.80 MB)
  ushort_t* wb    = (ushort_t*)(ws_f + 200704);  // 2*256*1024 ushorts (1 MB)
  ushort_t* af    = wb + 2 * OO * CC;            // 128*32*1024 bf16  (8 MB)

  k_prep<<<dim3(256 + 2048), 256, 0, stream>>>(x, w_max, w_med, partial, wb);
  k_extract<<<dim3(NB * 8), 256, 0, stream>>>(x, partial, af);
  k_main<<<dim3(NB, 2), 512, 0, stream>>>(partial, wb, af,
                                          g_max, b_max, m_max, v_max,
                                          g_med, b_med, m_med, v_med, out);
}